// Round 19
// baseline (100.398 us; speedup 1.0000x reference)
//
#include <hip/hip_runtime.h>
#include <hip/hip_bf16.h>

// Shapes
#define B_SZ   256
#define C_SZ   1024
#define HW     49
#define KDIM   50176        // C*H*W
#define DHID   768
#define NCLS   5

typedef __bf16 bf16x8 __attribute__((ext_vector_type(8)));
typedef __bf16 bf16x4 __attribute__((ext_vector_type(4)));
typedef float  f32x4  __attribute__((ext_vector_type(4)));

#define GLOAD_LDS16(gsrc, ldst) \
  __builtin_amdgcn_global_load_lds((__attribute__((address_space(1))) void*)(gsrc), \
                                   (__attribute__((address_space(3))) void*)(ldst), 16, 0, 0)

#define BARRIER() do { \
    asm volatile("s_waitcnt lgkmcnt(0)" ::: "memory"); \
    __builtin_amdgcn_s_barrier(); \
    asm volatile("" ::: "memory"); \
  } while (0)

// ---------------------------------------------------------------------------
// Kernel A: per-(b,c) spatial max, pcam = feat*max -> bf16, feat copy -> out.
// ---------------------------------------------------------------------------
__global__ __launch_bounds__(256) void pcam_kernel(const float* __restrict__ feat,
                                                   float* __restrict__ feat_out,
                                                   __bf16* __restrict__ pcam) {
  __shared__ float sv[1568];
  __shared__ float smax[32];
  const int tid = threadIdx.x;
  const size_t base = (size_t)blockIdx.x * 1568;

  const float4* src4 = (const float4*)(feat + base);
  float4* dst4 = (float4*)(feat_out + base);
  #pragma unroll
  for (int i = 0; i < 2; ++i) {
    int idx = tid + i * 256;
    if (idx < 392) {
      float4 v = src4[idx];
      dst4[idx] = v;
      ((float4*)sv)[idx] = v;
    }
  }
  __syncthreads();

  {
    const int r = tid >> 3, p = tid & 7;
    float mx = -INFINITY;
    for (int i = p; i < HW; i += 8) mx = fmaxf(mx, sv[r * HW + i]);
    #pragma unroll
    for (int off = 1; off < 8; off <<= 1) mx = fmaxf(mx, __shfl_xor(mx, off));
    if (p == 0) smax[r] = mx;
  }
  __syncthreads();

  for (int i = tid; i < 1568; i += 256) {
    int r = (i * 1338) >> 16;        // i/49 exact for i<1568
    float v = sv[i] * smax[r];
    pcam[base + i] = (__bf16)v;
  }
}

// ---------------------------------------------------------------------------
// Kernel B (v17 = R16 patterns @ 2 BLOCKS/CU): R16/R18 ran 8 waves/CU and
// got 13-18 GB/s/CU service; fill/pcam (24-32 waves/CU) get 27-28; m97
// (3 blocks/CU) got 52. Occupancy-driven memory parallelism is the last
// untested lever with the coalesced pattern. Config: single-buf A (32KB
// DMA) + double-buf B (2x16KB) = 64KB LDS -> 2 blocks/CU; launch_bounds
// (512,4) caps VGPR at 128; NT=6 x KSPLIT=85 = 510 blocks. Per step:
// COMPUTE -> vmcnt(0)+WRITE_B -> barrier -> ISSUE_A(s+1)+ISSUE_B(s+2) ->
// vmcnt(4) (A landed, B(s+2) in flight) -> barrier. The co-resident block
// covers this block's stage waits.
// ---------------------------------------------------------------------------
#define BM 256
#define BN 128
#define BK 64
#define NT 6
#define KSPLIT 85
#define KSTEPS 784          // KDIM/BK

__global__ __launch_bounds__(512, 4) void gemm1_kernel(const __bf16* __restrict__ pcam,
                                                       const float* __restrict__ W1,
                                                       __bf16* __restrict__ h_part) {
  __shared__ __bf16 Asm[BM * BK];      // 32 KB (single buffer)
  __shared__ __bf16 Bsm[2][BN * BK];   // 2 x 16 KB

  const int tid  = threadIdx.x;
  const int lane = tid & 63;
  const int w    = tid >> 6;        // 0..7
  const int wm   = w >> 2;          // 0..1 : 128-row slab
  const int wn   = w & 3;           // 0..3 : 32-col slab
  const int c_   = lane & 15;
  const int q_   = lane >> 4;       // 0..3
  const int n0   = blockIdx.x * BN;
  const int ks   = blockIdx.y;
  const int s0   = (ks * KSTEPS) / KSPLIT;
  const int s1   = ((ks + 1) * KSTEPS) / KSPLIT;   // 9-10 steps

  // ---- A staging (global_load_lds, R16 verbatim): 2048 16B-units, 4/thread;
  // row m=ug>>3; source unit (ug&7)^(m&7); dest linear.
  unsigned a_off[4];
  #pragma unroll
  for (int it = 0; it < 4; ++it) {
    const unsigned ug = it * 512 + tid;
    const unsigned m  = ug >> 3;
    a_off[it] = m * (unsigned)KDIM + (((ug & 7) ^ (m & 7)) * 8u);
  }

  // ---- B staging (coalesced, R16 verbatim): instr i reads rows w*16+i*4+q_,
  // 16B at c_*16 within the row's 256B chunk -> 4 rows x 256B contiguous.
  const float* bsrc[4];
  #pragma unroll
  for (int i = 0; i < 4; ++i)
    bsrc[i] = W1 + (size_t)(n0 + w * 16 + i * 4 + q_) * KDIM + c_ * 4;

  int bwr[4];
  #pragma unroll
  for (int i = 0; i < 4; ++i) {
    const int r = w * 16 + i * 4 + q_;
    bwr[i] = r * 128 + (((c_ >> 1) ^ (r & 7)) << 4) + ((c_ & 1) << 3);
  }

  f32x4 acc[8][2];
  #pragma unroll
  for (int i = 0; i < 8; ++i)
    #pragma unroll
    for (int j = 0; j < 2; ++j) acc[i][j] = f32x4{0.f, 0.f, 0.f, 0.f};

  f32x4 bq0, bq1, bq2, bq3;          // B stage regs (one K-step)

#define ISSUE_A(s) do { \
    const unsigned ka = (unsigned)(s) * BK; \
    _Pragma("unroll") \
    for (int it = 0; it < 4; ++it) \
      GLOAD_LDS16(pcam + a_off[it] + ka, (char*)Asm + it * 8192 + w * 1024); \
  } while (0)

#define ISSUE_B(s) do { \
    const size_t kb = (size_t)(s) * BK; \
    bq0 = *(const f32x4*)(bsrc[0] + kb); \
    bq1 = *(const f32x4*)(bsrc[1] + kb); \
    bq2 = *(const f32x4*)(bsrc[2] + kb); \
    bq3 = *(const f32x4*)(bsrc[3] + kb); \
  } while (0)

#define WRITE_B(bi) do { \
    _Pragma("unroll") \
    for (int i = 0; i < 4; ++i) { \
      const f32x4 v = (i == 0) ? bq0 : (i == 1) ? bq1 : (i == 2) ? bq2 : bq3; \
      bf16x4 bv; \
      bv[0] = (__bf16)v[0]; bv[1] = (__bf16)v[1]; \
      bv[2] = (__bf16)v[2]; bv[3] = (__bf16)v[3]; \
      *(bf16x4*)((char*)Bsm[bi] + bwr[i]) = bv; \
    } \
  } while (0)

// Wave (wm,wn): rows wm*128+i*16 (i<8), cols wn*32+j*16 (j<2).
#define COMPUTE(bi) do { \
    _Pragma("unroll") \
    for (int ksub = 0; ksub < 2; ++ksub) { \
      const int u = ksub * 4 + q_; \
      bf16x8 bfr[2]; \
      _Pragma("unroll") \
      for (int j = 0; j < 2; ++j) { \
        const int rn = wn * 32 + j * 16 + c_; \
        bfr[j] = *(const bf16x8*)((const char*)Bsm[bi] + rn * 128 + ((u ^ (rn & 7)) << 4)); \
      } \
      _Pragma("unroll") \
      for (int i = 0; i < 8; ++i) { \
        const int m = wm * 128 + i * 16 + c_; \
        const bf16x8 af = *(const bf16x8*)((const char*)Asm + m * 128 + ((u ^ (m & 7)) << 4)); \
        acc[i][0] = __builtin_amdgcn_mfma_f32_16x16x32_bf16(af, bfr[0], acc[i][0], 0, 0, 0); \
        acc[i][1] = __builtin_amdgcn_mfma_f32_16x16x32_bf16(af, bfr[1], acc[i][1], 0, 0, 0); \
      } \
    } \
  } while (0)

  // ---- prologue: A(s0)+B(s0) staged, B(s0+1) issued
  ISSUE_A(s0);
  ISSUE_B(s0);
  asm volatile("s_waitcnt vmcnt(0)" ::: "memory");
  WRITE_B(0);
  BARRIER();
  if (s0 + 1 < s1) ISSUE_B(s0 + 1);

  for (int s = s0; s < s1; ++s) {
    const int cur = (s - s0) & 1;
    COMPUTE(cur);
    if (s + 1 < s1) {
      asm volatile("s_waitcnt vmcnt(0)" ::: "memory");  // B(s+1) regs landed
      WRITE_B(cur ^ 1);
      BARRIER();                                        // A reads done; B writes visible
      ISSUE_A(s + 1);                                   // DMA into single A buffer
      if (s + 2 < s1) {
        ISSUE_B(s + 2);
        asm volatile("s_waitcnt vmcnt(4)" ::: "memory"); // A(s+1) landed; B(s+2) rides
      } else {
        asm volatile("s_waitcnt vmcnt(0)" ::: "memory");
      }
      BARRIER();                                        // all waves' A DMA done
    }
  }

  // ---- epilogue: bf16 partial slice [ks][n][m] (m fastest, 4 per lane)
  __bf16* out = h_part + (size_t)ks * DHID * B_SZ;
  #pragma unroll
  for (int j = 0; j < 2; ++j) {
    const int n = n0 + wn * 32 + j * 16 + c_;
    #pragma unroll
    for (int i = 0; i < 8; ++i) {
      const int mb = wm * 128 + i * 16 + q_ * 4;
      bf16x4 pv;
      pv[0] = (__bf16)acc[i][j][0]; pv[1] = (__bf16)acc[i][j][1];
      pv[2] = (__bf16)acc[i][j][2]; pv[3] = (__bf16)acc[i][j][3];
      *(bf16x4*)(out + (size_t)n * B_SZ + mb) = pv;
    }
  }
#undef ISSUE_A
#undef ISSUE_B
#undef WRITE_B
#undef COMPUTE
}

// ---------------------------------------------------------------------------
// Kernel C: reduce bf16 split-K partials, add b1, relu -> h[m][n] (fp32)
// ---------------------------------------------------------------------------
__global__ __launch_bounds__(256) void reduce_kernel(const __bf16* __restrict__ h_part,
                                                     const float* __restrict__ b1,
                                                     float* __restrict__ h) {
  const int n = blockIdx.x;
  const int m = threadIdx.x;
  float s = 0.f;
  #pragma unroll 5
  for (int ks = 0; ks < KSPLIT; ++ks)
    s += (float)h_part[((size_t)ks * DHID + n) * B_SZ + m];
  float v = s + b1[n];
  h[(size_t)m * DHID + n] = v > 0.f ? v : 0.f;
}

// ---------------------------------------------------------------------------
// Kernel D: logits = h @ W2^T + b2. One wave per batch row.
// ---------------------------------------------------------------------------
__global__ __launch_bounds__(64) void head_kernel(const float* __restrict__ h,
                                                  const float* __restrict__ W2,
                                                  const float* __restrict__ b2,
                                                  float* __restrict__ logits) {
  const int m = blockIdx.x;
  const int lane = threadIdx.x;
  float hv[12];
  #pragma unroll
  for (int j = 0; j < 12; ++j) hv[j] = h[(size_t)m * DHID + j * 64 + lane];
  #pragma unroll
  for (int c = 0; c < NCLS; ++c) {
    float s = 0.f;
    #pragma unroll
    for (int j = 0; j < 12; ++j) s += hv[j] * W2[c * DHID + j * 64 + lane];
    #pragma unroll
    for (int off = 32; off > 0; off >>= 1) s += __shfl_xor(s, off);
    if (lane == 0) logits[m * NCLS + c] = s + b2[c];
  }
}

// ---------------------------------------------------------------------------
extern "C" void kernel_launch(void* const* d_in, const int* in_sizes, int n_in,
                              void* d_out, int out_size, void* d_ws, size_t ws_size,
                              hipStream_t stream) {
  const float* feat = (const float*)d_in[0];
  const float* W1   = (const float*)d_in[1];
  const float* b1   = (const float*)d_in[2];
  const float* W2   = (const float*)d_in[3];
  const float* b2   = (const float*)d_in[4];

  float* logits   = (float*)d_out;
  float* feat_out = (float*)d_out + (size_t)B_SZ * NCLS;

  char* ws = (char*)d_ws;
  __bf16* pcam   = (__bf16*)ws;                                   // 25.7 MB
  __bf16* h_part = (__bf16*)(ws + (size_t)B_SZ * KDIM * 2);       // 85*768*256*2 = 33.4 MB
  float*  h      = (float*)(ws + (size_t)B_SZ * KDIM * 2
                               + (size_t)KSPLIT * DHID * B_SZ * 2); // 786 KB

  pcam_kernel<<<(B_SZ * C_SZ) / 32, 256, 0, stream>>>(feat, feat_out, pcam);
  gemm1_kernel<<<dim3(NT, KSPLIT), 512, 0, stream>>>(pcam, W1, h_part);
  reduce_kernel<<<DHID, 256, 0, stream>>>(h_part, b1, h);
  head_kernel<<<B_SZ, 64, 0, stream>>>(h, W2, b2, logits);
}

// Round 20
// 99.307 us; speedup vs baseline: 1.0110x; 1.0110x over previous
//
#include <hip/hip_runtime.h>
#include <hip/hip_bf16.h>

// Shapes
#define B_SZ   256
#define C_SZ   1024
#define HW     49
#define KDIM   50176        // C*H*W
#define DHID   768
#define NCLS   5

typedef __bf16 bf16x8 __attribute__((ext_vector_type(8)));
typedef __bf16 bf16x4 __attribute__((ext_vector_type(4)));
typedef float  f32x4  __attribute__((ext_vector_type(4)));

#define GLOAD_LDS16(gsrc, ldst) \
  __builtin_amdgcn_global_load_lds((__attribute__((address_space(1))) void*)(gsrc), \
                                   (__attribute__((address_space(3))) void*)(ldst), 16, 0, 0)

#define FENCE()   asm volatile("" ::: "memory")
#define BARRIER() do { \
    asm volatile("s_waitcnt lgkmcnt(0)" ::: "memory"); \
    __builtin_amdgcn_s_barrier(); \
    asm volatile("" ::: "memory"); \
  } while (0)

// ---------------------------------------------------------------------------
// Kernel A: per-(b,c) spatial max, pcam = feat*max -> bf16, feat copy -> out.
// (Copy lives here: the feat read is shared with the max pass, so the copy
// adds only the 51MB write; R17 proved gemm has no ingress slack for it.)
// ---------------------------------------------------------------------------
__global__ __launch_bounds__(256) void pcam_kernel(const float* __restrict__ feat,
                                                   float* __restrict__ feat_out,
                                                   __bf16* __restrict__ pcam) {
  __shared__ float sv[1568];
  __shared__ float smax[32];
  const int tid = threadIdx.x;
  const size_t base = (size_t)blockIdx.x * 1568;

  const float4* src4 = (const float4*)(feat + base);
  float4* dst4 = (float4*)(feat_out + base);
  #pragma unroll
  for (int i = 0; i < 2; ++i) {
    int idx = tid + i * 256;
    if (idx < 392) {
      float4 v = src4[idx];
      dst4[idx] = v;
      ((float4*)sv)[idx] = v;
    }
  }
  __syncthreads();

  {
    const int r = tid >> 3, p = tid & 7;
    float mx = -INFINITY;
    for (int i = p; i < HW; i += 8) mx = fmaxf(mx, sv[r * HW + i]);
    #pragma unroll
    for (int off = 1; off < 8; off <<= 1) mx = fmaxf(mx, __shfl_xor(mx, off));
    if (p == 0) smax[r] = mx;
  }
  __syncthreads();

  for (int i = tid; i < 1568; i += 256) {
    int r = (i * 1338) >> 16;        // i/49 exact for i<1568
    float v = sv[i] * smax[r];
    pcam[base + i] = (__bf16)v;
  }
}

// ---------------------------------------------------------------------------
// Kernel B (v18 = R16 + SPLIT DRAIN): R16 (best, 92.7us) drained vmcnt(0)
// for B-regs AND A-DMA before WRITE_B, though WRITE_B needs only B. Here B
// is issued BEFORE A (so B entries are OLDER in the in-order vm counter):
//   vmcnt(4) -> B(s+1) landed, A(s+1) still flying -> WRITE_B overlaps the
//   A tail -> vmcnt(0) -> BARRIER.
// Everything else R16-verbatim: BM=256, BN=128, BK=64, wave quadrants
// (2Mx4N, tile 128x32), coalesced reg-staged B (4 instr = 4rows x 256B
// contiguous), XOR-swizzled ds_write/ds_read, A via gload_lds DMA
// (source-swizzled, linear dest), double-buffered 96KB LDS, ONE barrier
// per K-step, bf16 partials [ks][n][m], NT=6 x KSPLIT=42 = 252 blocks.
// ---------------------------------------------------------------------------
#define BM 256
#define BN 128
#define BK 64
#define NT 6
#define KSPLIT 42
#define KSTEPS 784          // KDIM/BK

__global__ __launch_bounds__(512, 1) void gemm1_kernel(const __bf16* __restrict__ pcam,
                                                       const float* __restrict__ W1,
                                                       __bf16* __restrict__ h_part) {
  __shared__ __bf16 Asm[2][BM * BK];   // 2 x 32 KB
  __shared__ __bf16 Bsm[2][BN * BK];   // 2 x 16 KB

  const int tid  = threadIdx.x;
  const int lane = tid & 63;
  const int w    = tid >> 6;        // 0..7
  const int wm   = w >> 2;          // 0..1 : 128-row slab
  const int wn   = w & 3;           // 0..3 : 32-col slab
  const int c_   = lane & 15;
  const int q_   = lane >> 4;       // 0..3
  const int n0   = blockIdx.x * BN;
  const int ks   = blockIdx.y;
  const int s0   = (ks * KSTEPS) / KSPLIT;
  const int s1   = ((ks + 1) * KSTEPS) / KSPLIT;

  // ---- A staging (global_load_lds): 2048 16B-units, 4/thread;
  // row m=ug>>3; source unit (ug&7)^(m&7); dest linear.
  unsigned a_off[4];
  #pragma unroll
  for (int it = 0; it < 4; ++it) {
    const unsigned ug = it * 512 + tid;
    const unsigned m  = ug >> 3;
    a_off[it] = m * (unsigned)KDIM + (((ug & 7) ^ (m & 7)) * 8u);
  }

  // ---- B staging (coalesced): instr i reads rows w*16+i*4+q_, 16B at c_*16
  // within the row's 256B chunk -> 4 rows x 256B contiguous per instr.
  const float* bsrc[4];
  #pragma unroll
  for (int i = 0; i < 4; ++i)
    bsrc[i] = W1 + (size_t)(n0 + w * 16 + i * 4 + q_) * KDIM + c_ * 4;

  int bwr[4];
  #pragma unroll
  for (int i = 0; i < 4; ++i) {
    const int r = w * 16 + i * 4 + q_;
    bwr[i] = r * 128 + (((c_ >> 1) ^ (r & 7)) << 4) + ((c_ & 1) << 3);
  }

  f32x4 acc[8][2];
  #pragma unroll
  for (int i = 0; i < 8; ++i)
    #pragma unroll
    for (int j = 0; j < 2; ++j) acc[i][j] = f32x4{0.f, 0.f, 0.f, 0.f};

  f32x4 bq0, bq1, bq2, bq3;          // B stage regs (one K-step)

#define ISSUE_A(bi, s) do { \
    const unsigned ka = (unsigned)(s) * BK; \
    _Pragma("unroll") \
    for (int it = 0; it < 4; ++it) \
      GLOAD_LDS16(pcam + a_off[it] + ka, (char*)Asm[bi] + it * 8192 + w * 1024); \
  } while (0)

#define ISSUE_B(s) do { \
    const size_t kb = (size_t)(s) * BK; \
    bq0 = *(const f32x4*)(bsrc[0] + kb); \
    bq1 = *(const f32x4*)(bsrc[1] + kb); \
    bq2 = *(const f32x4*)(bsrc[2] + kb); \
    bq3 = *(const f32x4*)(bsrc[3] + kb); \
  } while (0)

#define WRITE_B(bi) do { \
    _Pragma("unroll") \
    for (int i = 0; i < 4; ++i) { \
      const f32x4 v = (i == 0) ? bq0 : (i == 1) ? bq1 : (i == 2) ? bq2 : bq3; \
      bf16x4 bv; \
      bv[0] = (__bf16)v[0]; bv[1] = (__bf16)v[1]; \
      bv[2] = (__bf16)v[2]; bv[3] = (__bf16)v[3]; \
      *(bf16x4*)((char*)Bsm[bi] + bwr[i]) = bv; \
    } \
  } while (0)

// Wave (wm,wn): rows wm*128+i*16 (i<8), cols wn*32+j*16 (j<2).
#define COMPUTE(bi) do { \
    _Pragma("unroll") \
    for (int ksub = 0; ksub < 2; ++ksub) { \
      const int u = ksub * 4 + q_; \
      bf16x8 bfr[2]; \
      _Pragma("unroll") \
      for (int j = 0; j < 2; ++j) { \
        const int rn = wn * 32 + j * 16 + c_; \
        bfr[j] = *(const bf16x8*)((const char*)Bsm[bi] + rn * 128 + ((u ^ (rn & 7)) << 4)); \
      } \
      _Pragma("unroll") \
      for (int i = 0; i < 8; ++i) { \
        const int m = wm * 128 + i * 16 + c_; \
        const bf16x8 af = *(const bf16x8*)((const char*)Asm[bi] + m * 128 + ((u ^ (m & 7)) << 4)); \
        acc[i][0] = __builtin_amdgcn_mfma_f32_16x16x32_bf16(af, bfr[0], acc[i][0], 0, 0, 0); \
        acc[i][1] = __builtin_amdgcn_mfma_f32_16x16x32_bf16(af, bfr[1], acc[i][1], 0, 0, 0); \
      } \
    } \
  } while (0)

  // ---- prologue: B(s0) then A(s0) (B older), drain, stage, barrier
  ISSUE_B(s0);
  FENCE();
  ISSUE_A(0, s0);
  FENCE();
  asm volatile("s_waitcnt vmcnt(0)" ::: "memory");
  WRITE_B(0);
  BARRIER();
  if (s0 + 1 < s1) {
    ISSUE_B(s0 + 1);      // B first -> older counter entries
    FENCE();
    ISSUE_A(1, s0 + 1);
    FENCE();
  }

  for (int s = s0; s < s1; ++s) {
    const int cur = (s - s0) & 1;
    COMPUTE(cur);
    if (s + 1 < s1) {
      // Outstanding (oldest->newest): B(s+1) x4, A(s+1) x4.
      asm volatile("s_waitcnt vmcnt(4)" ::: "memory");  // B(s+1) landed; A tail flies
      WRITE_B(cur ^ 1);                                 // overlaps A-DMA tail
      asm volatile("s_waitcnt vmcnt(0)" ::: "memory");  // A(s+1) in LDS
    }
    BARRIER();
    if (s + 2 < s1) {
      ISSUE_B(s + 2);
      FENCE();
      ISSUE_A(cur, s + 2);
      FENCE();
    }
  }

  // ---- epilogue: bf16 partial slice [ks][n][m] (m fastest, 4 per lane)
  __bf16* out = h_part + (size_t)ks * DHID * B_SZ;
  #pragma unroll
  for (int j = 0; j < 2; ++j) {
    const int n = n0 + wn * 32 + j * 16 + c_;
    #pragma unroll
    for (int i = 0; i < 8; ++i) {
      const int mb = wm * 128 + i * 16 + q_ * 4;
      bf16x4 pv;
      pv[0] = (__bf16)acc[i][j][0]; pv[1] = (__bf16)acc[i][j][1];
      pv[2] = (__bf16)acc[i][j][2]; pv[3] = (__bf16)acc[i][j][3];
      *(bf16x4*)(out + (size_t)n * B_SZ + mb) = pv;
    }
  }
#undef ISSUE_A
#undef ISSUE_B
#undef WRITE_B
#undef COMPUTE
}

// ---------------------------------------------------------------------------
// Kernel C: reduce bf16 split-K partials, add b1, relu -> h[m][n] (fp32)
// ---------------------------------------------------------------------------
__global__ __launch_bounds__(256) void reduce_kernel(const __bf16* __restrict__ h_part,
                                                     const float* __restrict__ b1,
                                                     float* __restrict__ h) {
  const int n = blockIdx.x;
  const int m = threadIdx.x;
  float s = 0.f;
  #pragma unroll 6
  for (int ks = 0; ks < KSPLIT; ++ks)
    s += (float)h_part[((size_t)ks * DHID + n) * B_SZ + m];
  float v = s + b1[n];
  h[(size_t)m * DHID + n] = v > 0.f ? v : 0.f;
}

// ---------------------------------------------------------------------------
// Kernel D: logits = h @ W2^T + b2. One wave per batch row.
// ---------------------------------------------------------------------------
__global__ __launch_bounds__(64) void head_kernel(const float* __restrict__ h,
                                                  const float* __restrict__ W2,
                                                  const float* __restrict__ b2,
                                                  float* __restrict__ logits) {
  const int m = blockIdx.x;
  const int lane = threadIdx.x;
  float hv[12];
  #pragma unroll
  for (int j = 0; j < 12; ++j) hv[j] = h[(size_t)m * DHID + j * 64 + lane];
  #pragma unroll
  for (int c = 0; c < NCLS; ++c) {
    float s = 0.f;
    #pragma unroll
    for (int j = 0; j < 12; ++j) s += hv[j] * W2[c * DHID + j * 64 + lane];
    #pragma unroll
    for (int off = 32; off > 0; off >>= 1) s += __shfl_xor(s, off);
    if (lane == 0) logits[m * NCLS + c] = s + b2[c];
  }
}

// ---------------------------------------------------------------------------
extern "C" void kernel_launch(void* const* d_in, const int* in_sizes, int n_in,
                              void* d_out, int out_size, void* d_ws, size_t ws_size,
                              hipStream_t stream) {
  const float* feat = (const float*)d_in[0];
  const float* W1   = (const float*)d_in[1];
  const float* b1   = (const float*)d_in[2];
  const float* W2   = (const float*)d_in[3];
  const float* b2   = (const float*)d_in[4];

  float* logits   = (float*)d_out;
  float* feat_out = (float*)d_out + (size_t)B_SZ * NCLS;

  char* ws = (char*)d_ws;
  __bf16* pcam   = (__bf16*)ws;                                   // 25.7 MB
  __bf16* h_part = (__bf16*)(ws + (size_t)B_SZ * KDIM * 2);       // 16.5 MB
  float*  h      = (float*)(ws + (size_t)B_SZ * KDIM * 2
                               + (size_t)KSPLIT * DHID * B_SZ * 2); // 786 KB

  pcam_kernel<<<(B_SZ * C_SZ) / 32, 256, 0, stream>>>(feat, feat_out, pcam);
  gemm1_kernel<<<dim3(NT, KSPLIT), 512, 0, stream>>>(pcam, W1, h_part);
  reduce_kernel<<<DHID, 256, 0, stream>>>(h_part, b1, h);
  head_kernel<<<B_SZ, 64, 0, stream>>>(h, W2, b2, logits);
}

// Round 21
// 93.201 us; speedup vs baseline: 1.0772x; 1.0655x over previous
//
#include <hip/hip_runtime.h>
#include <hip/hip_bf16.h>

// Shapes
#define B_SZ   256
#define C_SZ   1024
#define HW     49
#define KDIM   50176        // C*H*W
#define DHID   768
#define NCLS   5

typedef __bf16 bf16x8 __attribute__((ext_vector_type(8)));
typedef __bf16 bf16x4 __attribute__((ext_vector_type(4)));
typedef float  f32x4  __attribute__((ext_vector_type(4)));

#define GLOAD_LDS16(gsrc, ldst) \
  __builtin_amdgcn_global_load_lds((__attribute__((address_space(1))) void*)(gsrc), \
                                   (__attribute__((address_space(3))) void*)(ldst), 16, 0, 0)

#define BARRIER() do { \
    asm volatile("s_waitcnt lgkmcnt(0)" ::: "memory"); \
    __builtin_amdgcn_s_barrier(); \
    asm volatile("" ::: "memory"); \
  } while (0)

// ---------------------------------------------------------------------------
// Kernel A: per-(b,c) spatial max, pcam = feat*max -> bf16, feat copy -> out.
// ---------------------------------------------------------------------------
__global__ __launch_bounds__(256) void pcam_kernel(const float* __restrict__ feat,
                                                   float* __restrict__ feat_out,
                                                   __bf16* __restrict__ pcam) {
  __shared__ float sv[1568];
  __shared__ float smax[32];
  const int tid = threadIdx.x;
  const size_t base = (size_t)blockIdx.x * 1568;

  const float4* src4 = (const float4*)(feat + base);
  float4* dst4 = (float4*)(feat_out + base);
  #pragma unroll
  for (int i = 0; i < 2; ++i) {
    int idx = tid + i * 256;
    if (idx < 392) {
      float4 v = src4[idx];
      dst4[idx] = v;
      ((float4*)sv)[idx] = v;
    }
  }
  __syncthreads();

  {
    const int r = tid >> 3, p = tid & 7;
    float mx = -INFINITY;
    for (int i = p; i < HW; i += 8) mx = fmaxf(mx, sv[r * HW + i]);
    #pragma unroll
    for (int off = 1; off < 8; off <<= 1) mx = fmaxf(mx, __shfl_xor(mx, off));
    if (p == 0) smax[r] = mx;
  }
  __syncthreads();

  for (int i = tid; i < 1568; i += 256) {
    int r = (i * 1338) >> 16;        // i/49 exact for i<1568
    float v = sv[i] * smax[r];
    pcam[base + i] = (__bf16)v;
  }
}

// ---------------------------------------------------------------------------
// Kernel B (R16 BEST, restored verbatim — 92.7us total): wave quadrants
// (2Mx4N, wave tile 128x32), coalesced reg-staged B (4 instr = 4 rows x
// 256B contiguous), XOR-swizzled ds_write/ds_read, A via gload_lds DMA
// (source-swizzled, linear dest), double-buffered 96KB LDS, single drain
// vmcnt(0) + ONE barrier per K-step, bf16 partials [ks][n][m].
// BM=256, BN=128, BK=64, NT=6, KSPLIT=42 -> 252 blocks, 1 blk/CU.
// R17-R20 falsified: copy-fusion (no ingress slack), NT=3 (service rate
// drops), 2 blk/CU (extra barrier), split-drain (issue-order disruption).
// ---------------------------------------------------------------------------
#define BM 256
#define BN 128
#define BK 64
#define NT 6
#define KSPLIT 42
#define KSTEPS 784          // KDIM/BK

__global__ __launch_bounds__(512, 1) void gemm1_kernel(const __bf16* __restrict__ pcam,
                                                       const float* __restrict__ W1,
                                                       __bf16* __restrict__ h_part) {
  __shared__ __bf16 Asm[2][BM * BK];   // 2 x 32 KB
  __shared__ __bf16 Bsm[2][BN * BK];   // 2 x 16 KB

  const int tid  = threadIdx.x;
  const int lane = tid & 63;
  const int w    = tid >> 6;        // 0..7
  const int wm   = w >> 2;          // 0..1 : 128-row slab
  const int wn   = w & 3;           // 0..3 : 32-col slab
  const int c_   = lane & 15;
  const int q_   = lane >> 4;       // 0..3
  const int n0   = blockIdx.x * BN;
  const int ks   = blockIdx.y;
  const int s0   = (ks * KSTEPS) / KSPLIT;
  const int s1   = ((ks + 1) * KSTEPS) / KSPLIT;

  // ---- A staging (global_load_lds): 2048 16B-units, 4/thread;
  // row m=ug>>3; source unit (ug&7)^(m&7); dest linear.
  unsigned a_off[4];
  #pragma unroll
  for (int it = 0; it < 4; ++it) {
    const unsigned ug = it * 512 + tid;
    const unsigned m  = ug >> 3;
    a_off[it] = m * (unsigned)KDIM + (((ug & 7) ^ (m & 7)) * 8u);
  }

  // ---- B staging (coalesced): instr i reads rows w*16+i*4+q_, 16B at c_*16
  // within the row's 256B chunk -> 4 rows x 256B contiguous per instr.
  const float* bsrc[4];
  #pragma unroll
  for (int i = 0; i < 4; ++i)
    bsrc[i] = W1 + (size_t)(n0 + w * 16 + i * 4 + q_) * KDIM + c_ * 4;

  int bwr[4];
  #pragma unroll
  for (int i = 0; i < 4; ++i) {
    const int r = w * 16 + i * 4 + q_;
    bwr[i] = r * 128 + (((c_ >> 1) ^ (r & 7)) << 4) + ((c_ & 1) << 3);
  }

  f32x4 acc[8][2];
  #pragma unroll
  for (int i = 0; i < 8; ++i)
    #pragma unroll
    for (int j = 0; j < 2; ++j) acc[i][j] = f32x4{0.f, 0.f, 0.f, 0.f};

  f32x4 bq0, bq1, bq2, bq3;          // B stage regs (one K-step)

#define ISSUE_A(bi, s) do { \
    const unsigned ka = (unsigned)(s) * BK; \
    _Pragma("unroll") \
    for (int it = 0; it < 4; ++it) \
      GLOAD_LDS16(pcam + a_off[it] + ka, (char*)Asm[bi] + it * 8192 + w * 1024); \
  } while (0)

#define ISSUE_B(s) do { \
    const size_t kb = (size_t)(s) * BK; \
    bq0 = *(const f32x4*)(bsrc[0] + kb); \
    bq1 = *(const f32x4*)(bsrc[1] + kb); \
    bq2 = *(const f32x4*)(bsrc[2] + kb); \
    bq3 = *(const f32x4*)(bsrc[3] + kb); \
  } while (0)

#define WRITE_B(bi) do { \
    _Pragma("unroll") \
    for (int i = 0; i < 4; ++i) { \
      const f32x4 v = (i == 0) ? bq0 : (i == 1) ? bq1 : (i == 2) ? bq2 : bq3; \
      bf16x4 bv; \
      bv[0] = (__bf16)v[0]; bv[1] = (__bf16)v[1]; \
      bv[2] = (__bf16)v[2]; bv[3] = (__bf16)v[3]; \
      *(bf16x4*)((char*)Bsm[bi] + bwr[i]) = bv; \
    } \
  } while (0)

// Wave (wm,wn): rows wm*128+i*16 (i<8), cols wn*32+j*16 (j<2).
#define COMPUTE(bi) do { \
    _Pragma("unroll") \
    for (int ksub = 0; ksub < 2; ++ksub) { \
      const int u = ksub * 4 + q_; \
      bf16x8 bfr[2]; \
      _Pragma("unroll") \
      for (int j = 0; j < 2; ++j) { \
        const int rn = wn * 32 + j * 16 + c_; \
        bfr[j] = *(const bf16x8*)((const char*)Bsm[bi] + rn * 128 + ((u ^ (rn & 7)) << 4)); \
      } \
      _Pragma("unroll") \
      for (int i = 0; i < 8; ++i) { \
        const int m = wm * 128 + i * 16 + c_; \
        const bf16x8 af = *(const bf16x8*)((const char*)Asm[bi] + m * 128 + ((u ^ (m & 7)) << 4)); \
        acc[i][0] = __builtin_amdgcn_mfma_f32_16x16x32_bf16(af, bfr[0], acc[i][0], 0, 0, 0); \
        acc[i][1] = __builtin_amdgcn_mfma_f32_16x16x32_bf16(af, bfr[1], acc[i][1], 0, 0, 0); \
      } \
    } \
  } while (0)

  // ---- prologue
  ISSUE_A(0, s0);
  ISSUE_B(s0);
  asm volatile("s_waitcnt vmcnt(0)" ::: "memory");
  WRITE_B(0);
  BARRIER();
  if (s0 + 1 < s1) { ISSUE_A(1, s0 + 1); ISSUE_B(s0 + 1); }

  for (int s = s0; s < s1; ++s) {
    const int cur = (s - s0) & 1;
    COMPUTE(cur);
    if (s + 1 < s1) {
      asm volatile("s_waitcnt vmcnt(0)" ::: "memory");  // A(s+1) DMA + B(s+1) regs
      WRITE_B(cur ^ 1);
    }
    BARRIER();
    if (s + 2 < s1) { ISSUE_A(cur, s + 2); ISSUE_B(s + 2); }
  }

  // ---- epilogue: bf16 partial slice [ks][n][m] (m fastest, 4 per lane)
  __bf16* out = h_part + (size_t)ks * DHID * B_SZ;
  #pragma unroll
  for (int j = 0; j < 2; ++j) {
    const int n = n0 + wn * 32 + j * 16 + c_;
    #pragma unroll
    for (int i = 0; i < 8; ++i) {
      const int mb = wm * 128 + i * 16 + q_ * 4;
      bf16x4 pv;
      pv[0] = (__bf16)acc[i][j][0]; pv[1] = (__bf16)acc[i][j][1];
      pv[2] = (__bf16)acc[i][j][2]; pv[3] = (__bf16)acc[i][j][3];
      *(bf16x4*)(out + (size_t)n * B_SZ + mb) = pv;
    }
  }
#undef ISSUE_A
#undef ISSUE_B
#undef WRITE_B
#undef COMPUTE
}

// ---------------------------------------------------------------------------
// Kernel C: reduce bf16 split-K partials, add b1, relu -> h[m][n] (fp32)
// ---------------------------------------------------------------------------
__global__ __launch_bounds__(256) void reduce_kernel(const __bf16* __restrict__ h_part,
                                                     const float* __restrict__ b1,
                                                     float* __restrict__ h) {
  const int n = blockIdx.x;
  const int m = threadIdx.x;
  float s = 0.f;
  #pragma unroll 6
  for (int ks = 0; ks < KSPLIT; ++ks)
    s += (float)h_part[((size_t)ks * DHID + n) * B_SZ + m];
  float v = s + b1[n];
  h[(size_t)m * DHID + n] = v > 0.f ? v : 0.f;
}

// ---------------------------------------------------------------------------
// Kernel D: logits = h @ W2^T + b2. One wave per batch row.
// ---------------------------------------------------------------------------
__global__ __launch_bounds__(64) void head_kernel(const float* __restrict__ h,
                                                  const float* __restrict__ W2,
                                                  const float* __restrict__ b2,
                                                  float* __restrict__ logits) {
  const int m = blockIdx.x;
  const int lane = threadIdx.x;
  float hv[12];
  #pragma unroll
  for (int j = 0; j < 12; ++j) hv[j] = h[(size_t)m * DHID + j * 64 + lane];
  #pragma unroll
  for (int c = 0; c < NCLS; ++c) {
    float s = 0.f;
    #pragma unroll
    for (int j = 0; j < 12; ++j) s += hv[j] * W2[c * DHID + j * 64 + lane];
    #pragma unroll
    for (int off = 32; off > 0; off >>= 1) s += __shfl_xor(s, off);
    if (lane == 0) logits[m * NCLS + c] = s + b2[c];
  }
}

// ---------------------------------------------------------------------------
extern "C" void kernel_launch(void* const* d_in, const int* in_sizes, int n_in,
                              void* d_out, int out_size, void* d_ws, size_t ws_size,
                              hipStream_t stream) {
  const float* feat = (const float*)d_in[0];
  const float* W1   = (const float*)d_in[1];
  const float* b1   = (const float*)d_in[2];
  const float* W2   = (const float*)d_in[3];
  const float* b2   = (const float*)d_in[4];

  float* logits   = (float*)d_out;
  float* feat_out = (float*)d_out + (size_t)B_SZ * NCLS;

  char* ws = (char*)d_ws;
  __bf16* pcam   = (__bf16*)ws;                                   // 25.7 MB
  __bf16* h_part = (__bf16*)(ws + (size_t)B_SZ * KDIM * 2);       // 16.5 MB
  float*  h      = (float*)(ws + (size_t)B_SZ * KDIM * 2
                               + (size_t)KSPLIT * DHID * B_SZ * 2); // 786 KB

  pcam_kernel<<<(B_SZ * C_SZ) / 32, 256, 0, stream>>>(feat, feat_out, pcam);
  gemm1_kernel<<<dim3(NT, KSPLIT), 512, 0, stream>>>(pcam, W1, h_part);
  reduce_kernel<<<DHID, 256, 0, stream>>>(h_part, b1, h);
  head_kernel<<<B_SZ, 64, 0, stream>>>(h, W2, b2, logits);
}